// Round 1
// baseline (8180.845 us; speedup 1.0000x reference)
//
#include <hip/hip_runtime.h>
#include <math.h>

typedef __bf16 bf16_t;
typedef __bf16 bf16x8 __attribute__((ext_vector_type(8)));
typedef float  f32x4  __attribute__((ext_vector_type(4)));

#define EMBED  620
#define ECH    1000
#define DCH    1000
#define VOCAB  30000
#define SRCLEN 50
#define TRGLEN 50
#define BATCH  32
#define NSTEP  49              // TRG-1 steps
#define MROWS  1568            // NSTEP*BATCH
#define MPAD   1664            // 13*128
#define KC2    3648            // combined2 padded width: 620 emb | 1000 h | 4 pad | 2000 ctx | 24 pad
#define COLH   620
#define COLCTX 1624
#define KANN   2048            // padded annotation feature dim (2000 -> 2048)
#define NPV    30080           // vocab padded to 235*128

// output layout (floats): preds (50,32,30000) | hidden (1,32,1000) | attns (50,50,32)
#define HID_OFF  48000000
#define ATTN_OFF 48032000

__device__ __forceinline__ f32x4 mfma16(bf16x8 a, bf16x8 b, f32x4 c) {
  return __builtin_amdgcn_mfma_f32_16x16x32_bf16(a, b, c, 0, 0, 0);
}

// ---------------- fp32 -> bf16 conversion with 2D zero-padding and optional column-shift
// dst col c: c < shift_col -> src col c ; shift_col <= c < shift_col+shift_amt -> 0 ; else src col c-shift_amt
__global__ void k_cvt(const float* __restrict__ src, int src_ld, int src_col0,
                      int rows, int cols,
                      bf16_t* __restrict__ dst, int dst_rows, int dst_cols,
                      int shift_col, int shift_amt)
{
  for (int r = blockIdx.x; r < dst_rows; r += gridDim.x) {
    bf16_t* d = dst + (size_t)r * dst_cols;
    for (int c = threadIdx.x; c < dst_cols; c += 256) {
      float v = 0.f;
      bool pad = (c >= shift_col && c < shift_col + shift_amt);
      int sc = (c >= shift_col) ? c - shift_amt : c;
      if (!pad && r < rows && sc < cols)
        v = src[(size_t)r * src_ld + src_col0 + sc];
      d[c] = (bf16_t)v;
    }
  }
}

// ---------------- embedding gather -> combined2 emb slot (bf16)
__global__ void k_embed(const int* __restrict__ tokens, const float* __restrict__ emb,
                        bf16_t* __restrict__ C2)
{
  int m = blockIdx.x;                 // 0..1567 = t*32 + b
  int t = m >> 5, b = m & 31;
  int tok = tokens[t * BATCH + b];
  const float* e = emb + (size_t)tok * EMBED;
  bf16_t* d = C2 + (size_t)m * KC2;
  for (int c = threadIdx.x; c < EMBED; c += 256) d[c] = (bf16_t)e[c];
}

// ---------------- 128x128 MFMA GEMM: C(MxN,fp32) = A(M,K)bf16 @ B(N,K)bf16^T + bias
__global__ __launch_bounds__(256) void k_gemm128(
    const bf16_t* __restrict__ A, int lda,
    const bf16_t* __restrict__ B, int ldb,
    float* __restrict__ C, long long ldc,
    const float* __restrict__ bias,
    int M, int N, int ktiles)
{
  __shared__ __align__(16) bf16_t As[128 * 40];
  __shared__ __align__(16) bf16_t Bs[128 * 40];
  int tid = threadIdx.x;
  int m0 = blockIdx.x * 128, n0 = blockIdx.y * 128;
  int wave = tid >> 6, lane = tid & 63;
  int wr = wave >> 1, wc = wave & 1;
  int l15 = lane & 15, q = lane >> 4;
  f32x4 acc[4][4];
  f32x4 zero = {0.f, 0.f, 0.f, 0.f};
#pragma unroll
  for (int i = 0; i < 4; i++)
#pragma unroll
    for (int j = 0; j < 4; j++) acc[i][j] = zero;

  int r0 = tid >> 2, kc0 = (tid & 3) * 8;   // staging chunk: 8 bf16 per 16B load
  const bf16_t* Ab = A + (size_t)m0 * lda;
  const bf16_t* Bb = B + (size_t)n0 * ldb;

  for (int kt = 0; kt < ktiles; ++kt) {
    int k0 = kt * 32;
    __syncthreads();
    *(float4*)&As[(r0     ) * 40 + kc0] = *(const float4*)&Ab[(size_t)(r0     ) * lda + k0 + kc0];
    *(float4*)&As[(r0 + 64) * 40 + kc0] = *(const float4*)&Ab[(size_t)(r0 + 64) * lda + k0 + kc0];
    *(float4*)&Bs[(r0     ) * 40 + kc0] = *(const float4*)&Bb[(size_t)(r0     ) * ldb + k0 + kc0];
    *(float4*)&Bs[(r0 + 64) * 40 + kc0] = *(const float4*)&Bb[(size_t)(r0 + 64) * ldb + k0 + kc0];
    __syncthreads();
    bf16x8 af[4], bfm[4];
#pragma unroll
    for (int i = 0; i < 4; i++) af[i]  = *(const bf16x8*)&As[(wr * 64 + i * 16 + l15) * 40 + q * 8];
#pragma unroll
    for (int j = 0; j < 4; j++) bfm[j] = *(const bf16x8*)&Bs[(wc * 64 + j * 16 + l15) * 40 + q * 8];
#pragma unroll
    for (int i = 0; i < 4; i++)
#pragma unroll
      for (int j = 0; j < 4; j++)
        acc[i][j] = mfma16(af[i], bfm[j], acc[i][j]);
  }

#pragma unroll
  for (int j = 0; j < 4; j++) {
    int n = n0 + wc * 64 + j * 16 + l15;
    if (n >= N) continue;
    float bs = bias ? bias[n] : 0.f;
#pragma unroll
    for (int i = 0; i < 4; i++) {
#pragma unroll
      for (int r = 0; r < 4; r++) {
        int m = m0 + wr * 64 + i * 16 + q * 4 + r;
        if (m < M) C[(size_t)m * ldc + n] = acc[i][j][r] + bs;
      }
    }
  }
}

// ---------------- skinny MFMA GEMM: C(32xN,fp32) = A(32,K)bf16 @ B(N,K)bf16^T (+bias)(+Cinit)(tanh?)
__global__ __launch_bounds__(256) void k_gemm32(
    const bf16_t* __restrict__ A, int lda,
    const bf16_t* __restrict__ B, int ldb,
    float* __restrict__ C, int ldc,
    const float* __restrict__ bias,
    const float* __restrict__ Cinit, int ldci,
    int N, int ktiles, int act_tanh)
{
  __shared__ __align__(16) bf16_t As[32 * 40];
  __shared__ __align__(16) bf16_t Bs[256 * 40];
  int tid = threadIdx.x;
  int n0 = blockIdx.x * 256;
  int wave = tid >> 6, lane = tid & 63;
  int l15 = lane & 15, q = lane >> 4;
  f32x4 acc[2][4];
  f32x4 zero = {0.f, 0.f, 0.f, 0.f};
#pragma unroll
  for (int i = 0; i < 2; i++)
#pragma unroll
    for (int j = 0; j < 4; j++) acc[i][j] = zero;

  int rb = tid >> 2, kc = (tid & 3) * 8;
  const bf16_t* Bb = B + (size_t)n0 * ldb;

  for (int kt = 0; kt < ktiles; ++kt) {
    int k0 = kt * 32;
    __syncthreads();
    if (tid < 128)
      *(float4*)&As[rb * 40 + kc] = *(const float4*)&A[(size_t)rb * lda + k0 + kc];
#pragma unroll
    for (int i = 0; i < 4; i++)
      *(float4*)&Bs[(rb + i * 64) * 40 + kc] = *(const float4*)&Bb[(size_t)(rb + i * 64) * ldb + k0 + kc];
    __syncthreads();
    bf16x8 af[2], bfm[4];
#pragma unroll
    for (int i = 0; i < 2; i++) af[i]  = *(const bf16x8*)&As[(i * 16 + l15) * 40 + q * 8];
#pragma unroll
    for (int j = 0; j < 4; j++) bfm[j] = *(const bf16x8*)&Bs[(wave * 64 + j * 16 + l15) * 40 + q * 8];
#pragma unroll
    for (int i = 0; i < 2; i++)
#pragma unroll
      for (int j = 0; j < 4; j++)
        acc[i][j] = mfma16(af[i], bfm[j], acc[i][j]);
  }

#pragma unroll
  for (int j = 0; j < 4; j++) {
    int n = n0 + wave * 64 + j * 16 + l15;
    if (n >= N) continue;
    float add = bias ? bias[n] : 0.f;
#pragma unroll
    for (int i = 0; i < 2; i++) {
#pragma unroll
      for (int r = 0; r < 4; r++) {
        int m = i * 16 + q * 4 + r;
        float v = acc[i][j][r] + add;
        if (Cinit) v += Cinit[(size_t)m * ldci + n];
        if (act_tanh) v = tanhf(v);
        C[(size_t)m * ldc + n] = v;
      }
    }
  }
}

// ---------------- copy h0 into bf16 mirrors
__global__ void k_h0copy(const float* __restrict__ h, bf16_t* __restrict__ h_bf,
                         bf16_t* __restrict__ C2)
{
  int i = blockIdx.x * 256 + threadIdx.x;
  if (i >= BATCH * DCH) return;
  int b = i / DCH, j = i - b * DCH;
  float v = h[i];
  h_bf[b * 1024 + j] = (bf16_t)v;
  C2[(size_t)b * KC2 + COLH + j] = (bf16_t)v;
}

// ---------------- attention scores: scores[s][b] = w_a . tanh(U[s,b,:] + wch[b,:])
__global__ __launch_bounds__(64) void k_scores(
    const float* __restrict__ U, const float* __restrict__ wch,
    const float* __restrict__ w_a, float* __restrict__ scores)
{
  int s = blockIdx.x, b = blockIdx.y;
  int lane = threadIdx.x;
  const float* u = U + (size_t)(s * BATCH + b) * DCH;
  const float* w = wch + (size_t)b * DCH;
  float acc = 0.f;
  for (int j = lane; j < DCH; j += 64)
    acc += w_a[j] * tanhf(u[j] + w[j]);
#pragma unroll
  for (int o = 32; o > 0; o >>= 1) acc += __shfl_down(acc, o, 64);
  if (lane == 0) scores[s * BATCH + b] = acc;
}

// ---------------- softmax over BATCH axis + context; writes ctx (bf16) into combined2 and attn row to out
__global__ __launch_bounds__(256) void k_context(
    const float* __restrict__ scores, const float* __restrict__ ann,
    bf16_t* __restrict__ dstC2, float* __restrict__ attn_out)
{
  __shared__ float sc[SRCLEN * BATCH];
  __shared__ float mx[SRCLEN], den[SRCLEN], wsh[SRCLEN];
  int b = blockIdx.x;
  int tid = threadIdx.x;
  for (int i = tid; i < SRCLEN * BATCH; i += 256) sc[i] = scores[i];
  __syncthreads();
  if (tid < SRCLEN) {
    float m = -1e30f;
    for (int bb = 0; bb < BATCH; ++bb) m = fmaxf(m, sc[tid * BATCH + bb]);
    float d = 0.f;
    for (int bb = 0; bb < BATCH; ++bb) d += expf(sc[tid * BATCH + bb] - m);
    mx[tid] = m; den[tid] = d;
    wsh[tid] = expf(sc[tid * BATCH + b] - m) / d;
  }
  __syncthreads();
  int e = blockIdx.y * 256 + tid;
  if (e < 2 * ECH) {
    float acc = 0.f;
    for (int s = 0; s < SRCLEN; ++s)
      acc += wsh[s] * ann[((size_t)s * BATCH + b) * (2 * ECH) + e];
    dstC2[(size_t)b * KC2 + COLCTX + e] = (bf16_t)acc;
  }
  if (blockIdx.x == 0 && blockIdx.y == 0) {
    for (int i = tid; i < SRCLEN * BATCH; i += 256) {
      int s = i >> 5;
      attn_out[i] = expf(sc[i] - mx[s]) / den[s];
    }
  }
}

// ---------------- GRU gate combine + h update; mirrors h into bf16 + combined2 of next step
__global__ void k_hnew(const float* __restrict__ gi, const float* __restrict__ gh,
                       float* __restrict__ h, bf16_t* __restrict__ h_bf,
                       bf16_t* __restrict__ dstC2, float* __restrict__ hid_out)
{
  int i = blockIdx.x * 256 + threadIdx.x;
  if (i >= BATCH * DCH) return;
  int b = i / DCH, j = i - b * DCH;
  const float* gib = gi + (size_t)b * 3 * DCH;
  const float* ghb = gh + (size_t)b * 3 * DCH;
  float r = 1.f / (1.f + expf(-(gib[j] + ghb[j])));
  float z = 1.f / (1.f + expf(-(gib[DCH + j] + ghb[DCH + j])));
  float n = tanhf(gib[2 * DCH + j] + r * ghb[2 * DCH + j]);
  float hp = h[i];
  float hn = (1.f - z) * n + z * hp;
  h[i] = hn;
  h_bf[b * 1024 + j] = (bf16_t)hn;
  if (dstC2) dstC2[(size_t)b * KC2 + COLH + j] = (bf16_t)hn;
  if (hid_out) hid_out[i] = hn;
}

// ---------------- row-wise log_softmax over VOCAB, in place
__global__ __launch_bounds__(256) void k_logsoftmax(float* __restrict__ logits)
{
  __shared__ float red[4];
  int row = blockIdx.x, tid = threadIdx.x;
  float* p = logits + (size_t)row * VOCAB;
  float m = -1e30f;
  for (int i = tid; i < VOCAB; i += 256) m = fmaxf(m, p[i]);
#pragma unroll
  for (int o = 32; o > 0; o >>= 1) m = fmaxf(m, __shfl_down(m, o, 64));
  if ((tid & 63) == 0) red[tid >> 6] = m;
  __syncthreads();
  float M = fmaxf(fmaxf(red[0], red[1]), fmaxf(red[2], red[3]));
  __syncthreads();
  float s = 0.f;
  for (int i = tid; i < VOCAB; i += 256) s += expf(p[i] - M);
#pragma unroll
  for (int o = 32; o > 0; o >>= 1) s += __shfl_down(s, o, 64);
  if ((tid & 63) == 0) red[tid >> 6] = s;
  __syncthreads();
  float L = M + logf(red[0] + red[1] + red[2] + red[3]);
  for (int i = tid; i < VOCAB; i += 256) p[i] -= L;
}

extern "C" void kernel_launch(void* const* d_in, const int* in_sizes, int n_in,
                              void* d_out, int out_size, void* d_ws, size_t ws_size,
                              hipStream_t stream)
{
  const int*   tokens = (const int*)  d_in[0];
  const float* ann    = (const float*)d_in[1];
  const float* emb    = (const float*)d_in[2];
  const float* W_h    = (const float*)d_in[3];
  const float* b_h    = (const float*)d_in[4];
  const float* W_c    = (const float*)d_in[5];
  const float* b_c    = (const float*)d_in[6];
  const float* w_a    = (const float*)d_in[7];
  const float* W_ih   = (const float*)d_in[8];
  const float* W_hh   = (const float*)d_in[9];
  const float* b_ih   = (const float*)d_in[10];
  const float* b_hh   = (const float*)d_in[11];
  const float* W_p    = (const float*)d_in[12];
  const float* b_p    = (const float*)d_in[13];
  float* out = (float*)d_out;

  // workspace carve-up
  size_t off = 0;
  char* wsb = (char*)d_ws;
  auto alloc = [&](size_t bytes) -> void* {
    void* p = wsb + off;
    off += (bytes + 255) & ~(size_t)255;
    return p;
  };
  bf16_t* Wp_bf  = (bf16_t*)alloc((size_t)NPV * KC2 * 2);     // 219.5 MB
  bf16_t* C2     = (bf16_t*)alloc((size_t)MPAD * KC2 * 2);    // combined2 (bf16), padded
  bf16_t* annb   = (bf16_t*)alloc((size_t)MPAD * KANN * 2);
  bf16_t* Wc1b   = (bf16_t*)alloc((size_t)1024 * 1024 * 2);
  bf16_t* Wc2b   = (bf16_t*)alloc((size_t)1024 * 2016 * 2);
  bf16_t* Wih1b  = (bf16_t*)alloc((size_t)3072 * 640 * 2);
  bf16_t* Wih2b  = (bf16_t*)alloc((size_t)3072 * 2016 * 2);
  bf16_t* Whhb   = (bf16_t*)alloc((size_t)3072 * 1024 * 2);
  bf16_t* Whb    = (bf16_t*)alloc((size_t)1024 * 1024 * 2);
  float*  U      = (float*) alloc((size_t)1600 * 1000 * 4);
  float*  gi_emb = (float*) alloc((size_t)MROWS * 3000 * 4);
  float*  wch    = (float*) alloc((size_t)32 * 1000 * 4);
  float*  scores = (float*) alloc((size_t)1600 * 4);
  float*  gi     = (float*) alloc((size_t)32 * 3000 * 4);
  float*  gh     = (float*) alloc((size_t)32 * 3000 * 4);
  float*  h      = (float*) alloc((size_t)32 * 1000 * 4);
  bf16_t* h_bf   = (bf16_t*)alloc((size_t)32 * 1024 * 2);
  if (off > ws_size) return;   // workspace too small — bail cleanly

  const int NOSHIFT = 1 << 30;

  // ---- weight/activation conversions to padded bf16 (every call: ws is re-poisoned)
  k_cvt<<<NPV,  256, 0, stream>>>(W_p,  3620, 0,    VOCAB, 3620, Wp_bf, NPV,  KC2,  1620, 4);
  k_cvt<<<MPAD, 256, 0, stream>>>(ann,  2000, 0,    1600,  2000, annb,  MPAD, KANN, NOSHIFT, 0);
  k_cvt<<<1024, 256, 0, stream>>>(W_c,  3000, 0,    1000,  1000, Wc1b,  1024, 1024, NOSHIFT, 0);
  k_cvt<<<1024, 256, 0, stream>>>(W_c,  3000, 1000, 1000,  2000, Wc2b,  1024, 2016, NOSHIFT, 0);
  k_cvt<<<3072, 256, 0, stream>>>(W_ih, 2620, 0,    3000,  620,  Wih1b, 3072, 640,  NOSHIFT, 0);
  k_cvt<<<3072, 256, 0, stream>>>(W_ih, 2620, 620,  3000,  2000, Wih2b, 3072, 2016, NOSHIFT, 0);
  k_cvt<<<3072, 256, 0, stream>>>(W_hh, 1000, 0,    3000,  1000, Whhb,  3072, 1024, NOSHIFT, 0);
  k_cvt<<<1024, 256, 0, stream>>>(W_h,  1000, 0,    1000,  1000, Whb,   1024, 1024, NOSHIFT, 0);
  k_embed<<<MROWS, 256, 0, stream>>>(tokens, emb, C2);

  // ---- batched precomputes
  // U = ann @ W_c[:,DCH:].T + b_c   (1600 x 1000, K=2000)
  k_gemm128<<<dim3(13, 8), 256, 0, stream>>>(annb, KANN, Wc2b, 2016, U, 1000, b_c, 1600, 1000, 63);
  // gi_emb = emb_all @ W_ih[:, :620].T + b_ih   (1568 x 3000, K=620)
  k_gemm128<<<dim3(13, 24), 256, 0, stream>>>(C2, KC2, Wih1b, 640, gi_emb, 3000, b_ih, MROWS, 3000, 20);
  // h0 = tanh(ann[0,:,ECH:] @ W_h.T + b_h)
  k_gemm32<<<4, 256, 0, stream>>>(annb + 1000, KANN, Whb, 1024, h, 1000, b_h, nullptr, 0, 1000, 32, 1);
  k_h0copy<<<125, 256, 0, stream>>>(h, h_bf, C2);

  // ---- zero preds[0] and attns[0]
  hipMemsetAsync(out, 0, (size_t)BATCH * VOCAB * 4, stream);
  hipMemsetAsync(out + ATTN_OFF, 0, (size_t)SRCLEN * BATCH * 4, stream);

  // ---- sequential recurrence (49 steps)
  for (int t = 0; t < NSTEP; ++t) {
    bf16_t* c2row = C2 + (size_t)t * BATCH * KC2;
    // wch = h @ W_c[:, :DCH].T
    k_gemm32<<<4, 256, 0, stream>>>(h_bf, 1024, Wc1b, 1024, wch, 1000,
                                    nullptr, nullptr, 0, 1000, 32, 0);
    k_scores<<<dim3(SRCLEN, BATCH), 64, 0, stream>>>(U, wch, w_a, scores);
    k_context<<<dim3(BATCH, 8), 256, 0, stream>>>(scores, ann, c2row,
                                                  out + ATTN_OFF + (size_t)(t + 1) * SRCLEN * BATCH);
    // gi = gi_emb[t] + ctx @ W_ih[:, 620:].T
    k_gemm32<<<12, 256, 0, stream>>>(c2row + COLCTX, KC2, Wih2b, 2016, gi, 3000,
                                     nullptr, gi_emb + (size_t)t * BATCH * 3000, 3000, 3000, 63, 0);
    // gh = h @ W_hh.T + b_hh
    k_gemm32<<<12, 256, 0, stream>>>(h_bf, 1024, Whhb, 1024, gh, 3000,
                                     b_hh, nullptr, 0, 3000, 32, 0);
    bf16_t* nxt = (t + 1 < NSTEP) ? C2 + (size_t)(t + 1) * BATCH * KC2 : nullptr;
    float*  hid = (t == NSTEP - 1) ? out + HID_OFF : nullptr;
    k_hnew<<<125, 256, 0, stream>>>(gi, gh, h, h_bf, nxt, hid);
  }

  // ---- batched prediction: logits = combined2 @ W_p.T + b_p, then log_softmax
  k_gemm128<<<dim3(13, 235), 256, 0, stream>>>(C2, KC2, Wp_bf, KC2,
                                               out + (size_t)BATCH * VOCAB, VOCAB, b_p,
                                               MROWS, VOCAB, KC2 / 32);
  k_logsoftmax<<<MROWS, 256, 0, stream>>>(out + (size_t)BATCH * VOCAB);
}